// Round 1
// baseline (195.475 us; speedup 1.0000x reference)
//
#include <hip/hip_runtime.h>
#include <hip/hip_bf16.h>

typedef __bf16 bf16x8 __attribute__((ext_vector_type(8)));
typedef __bf16 bf16x4 __attribute__((ext_vector_type(4)));
typedef float  f32x4  __attribute__((ext_vector_type(4)));

#define MFMA16(a, b, c) __builtin_amdgcn_mfma_f32_16x16x32_bf16((a), (b), (c), 0, 0, 0)

// Problem constants
// B=8, N=1024, D=512, H=8, DH=64

// ---------------------------------------------------------------------------
// Kernel 1: fused QKV projection.  y = x @ W^T  for W in {Wq,Wk,Wv}.
// x: [8192,512] f32 row-major.  W: [512,512] f32 row-major (rows = out cols).
// Output layout: [b][h][n][dh] bf16.  q scaled by DH^-0.5 = 0.125.
// Block tile 64x64, 4 waves (2x2), K-step 32.  grid (128 row panels, 24).
// blockIdx.x fastest => row panel p always lands on XCD p%8 -> x L2-resident.
// ---------------------------------------------------------------------------
__global__ __launch_bounds__(256) void gemm_qkv(
    const float* __restrict__ x,
    const float* __restrict__ Wq, const float* __restrict__ Wk,
    const float* __restrict__ Wv,
    __bf16* __restrict__ qo, __bf16* __restrict__ ko, __bf16* __restrict__ vo)
{
    __shared__ __bf16 As[64][40];   // pad to 40 bf16 (80B rows) for bank spread
    __shared__ __bf16 Bs[64][40];
    const int tid  = threadIdx.x;
    const int lane = tid & 63;
    const int wid  = tid >> 6;
    const int g    = lane >> 4, l16 = lane & 15;
    const int wr   = wid >> 1,  wc  = wid & 1;
    const int r0   = blockIdx.x * 64;
    const int widx = blockIdx.y >> 3;          // 0=q 1=k 2=v
    const int c0   = (blockIdx.y & 7) * 64;
    const float* W = (widx == 0) ? Wq : (widx == 1 ? Wk : Wv);

    const int sr  = tid >> 3;   // 0..31 staging row (two passes)
    const int scq = tid & 7;    // float4 index within 32-float row

    f32x4 acc[2][2] = {};

    for (int k0 = 0; k0 < 512; k0 += 32) {
        __syncthreads();
#pragma unroll
        for (int j = 0; j < 2; ++j) {
            const int r = sr + 32 * j;
            float4 av = *reinterpret_cast<const float4*>(x + (size_t)(r0 + r) * 512 + k0 + scq * 4);
            float4 bv = *reinterpret_cast<const float4*>(W + (size_t)(c0 + r) * 512 + k0 + scq * 4);
            bf16x4 ap = { (__bf16)av.x, (__bf16)av.y, (__bf16)av.z, (__bf16)av.w };
            bf16x4 bp = { (__bf16)bv.x, (__bf16)bv.y, (__bf16)bv.z, (__bf16)bv.w };
            *reinterpret_cast<bf16x4*>(&As[r][scq * 4]) = ap;
            *reinterpret_cast<bf16x4*>(&Bs[r][scq * 4]) = bp;
        }
        __syncthreads();
        bf16x8 af[2], bfr[2];
#pragma unroll
        for (int rt = 0; rt < 2; ++rt)
            af[rt] = *reinterpret_cast<const bf16x8*>(&As[wr * 32 + rt * 16 + l16][g * 8]);
#pragma unroll
        for (int ct = 0; ct < 2; ++ct)
            bfr[ct] = *reinterpret_cast<const bf16x8*>(&Bs[wc * 32 + ct * 16 + l16][g * 8]);
#pragma unroll
        for (int rt = 0; rt < 2; ++rt)
#pragma unroll
            for (int ct = 0; ct < 2; ++ct)
                acc[rt][ct] = MFMA16(af[rt], bfr[ct], acc[rt][ct]);
    }

    __bf16* dst = (widx == 0) ? qo : (widx == 1 ? ko : vo);
    const float scale = (widx == 0) ? 0.125f : 1.0f;
#pragma unroll
    for (int rt = 0; rt < 2; ++rt)
#pragma unroll
        for (int ct = 0; ct < 2; ++ct)
#pragma unroll
            for (int reg = 0; reg < 4; ++reg) {
                int r = r0 + wr * 32 + rt * 16 + 4 * g + reg;
                int c = c0 + wc * 32 + ct * 16 + l16;
                float val = acc[rt][ct][reg] * scale;
                int b = r >> 10, n = r & 1023, h = c >> 6, dh = c & 63;
                dst[(((size_t)b * 8 + h) * 1024 + n) * 64 + dh] = (__bf16)val;
            }
}

// ---------------------------------------------------------------------------
// Kernel 2: transpose V  [b][h][n][dh] -> [b][h][dh][n]  (bf16, 64x64 tiles)
// ---------------------------------------------------------------------------
__global__ __launch_bounds__(256) void transpose_v(
    const __bf16* __restrict__ v, __bf16* __restrict__ vt)
{
    __shared__ __bf16 t[64][80];
    const int bh = blockIdx.y;
    const int n0 = blockIdx.x * 64;
    const int tid = threadIdx.x;
    const int r = tid >> 2, c = tid & 3;
#pragma unroll
    for (int j = 0; j < 2; ++j) {
        int ch = c + 4 * j;
        bf16x8 val = *reinterpret_cast<const bf16x8*>(v + ((size_t)bh * 1024 + n0 + r) * 64 + ch * 8);
        *reinterpret_cast<bf16x8*>(&t[r][ch * 8]) = val;
    }
    __syncthreads();
#pragma unroll
    for (int j = 0; j < 2; ++j) {
        int ch = c + 4 * j;
        bf16x8 o;
#pragma unroll
        for (int e = 0; e < 8; ++e) o[e] = t[ch * 8 + e][r];
        *reinterpret_cast<bf16x8*>(vt + ((size_t)bh * 64 + r) * 1024 + n0 + ch * 8) = o;
    }
}

// ---------------------------------------------------------------------------
// Kernel 3: fused flash attention with pair bias, all 8 heads per block.
// Block: (b, n-tile of 32 Q rows), 8 waves, wave w = head w.
// m-loop over 32 K/V rows: stage bias[b, n0:32, m0:32, 0:8] coalesced -> LDS
// planes [h][n][m], QK^T MFMA, +bias, online softmax, P->LDS bounce, PV MFMA.
// ---------------------------------------------------------------------------
__global__ __launch_bounds__(512) void attn_kernel(
    const __bf16* __restrict__ qw, const __bf16* __restrict__ kw,
    const __bf16* __restrict__ vtw, const float* __restrict__ bias,
    __bf16* __restrict__ ow)
{
    __shared__ float  bsm[8 * 1060];       // plane stride 1060 (h->+4 banks)
    __shared__ __bf16 psm[8][32][40];      // per-wave P bounce, 80B rows
    const int tid  = threadIdx.x;
    const int w    = tid >> 6;             // head
    const int lane = tid & 63;
    const int g    = lane >> 4, l16 = lane & 15;
    const int b    = blockIdx.y;
    const int n0   = blockIdx.x * 32;
    const size_t bh = (size_t)b * 8 + w;

    // Q fragments (A operand), resident for the whole kernel
    bf16x8 qf[2][2];
#pragma unroll
    for (int rt = 0; rt < 2; ++rt)
#pragma unroll
        for (int kc = 0; kc < 2; ++kc)
            qf[rt][kc] = *reinterpret_cast<const bf16x8*>(
                qw + (bh * 1024 + n0 + rt * 16 + l16) * 64 + kc * 32 + g * 8);

    f32x4 o[2][4] = {};
    float mrun[2][4], lrun[2][4];
#pragma unroll
    for (int rt = 0; rt < 2; ++rt)
#pragma unroll
        for (int reg = 0; reg < 4; ++reg) { mrun[rt][reg] = -1e30f; lrun[rt][reg] = 0.f; }

    const float* bias_b = bias + ((size_t)b * 1024 + n0) * 8192;  // n stride 8192, m stride 8
    const int snn = tid >> 4, sfi = tid & 15;

    for (int m0 = 0; m0 < 1024; m0 += 32) {
        __syncthreads();  // previous iter's bsm/psm reads complete
        {
            const float* src = bias_b + (size_t)snn * 8192 + (size_t)m0 * 8;
#pragma unroll
            for (int j = 0; j < 4; ++j) {
                int f4 = sfi + 16 * j;                   // 0..63 float4 within row chunk
                float4 v4 = *reinterpret_cast<const float4*>(src + f4 * 4);
                int mm = f4 >> 1;
                int h0 = (f4 & 1) * 4;
                bsm[(h0 + 0) * 1060 + snn * 33 + mm] = v4.x;
                bsm[(h0 + 1) * 1060 + snn * 33 + mm] = v4.y;
                bsm[(h0 + 2) * 1060 + snn * 33 + mm] = v4.z;
                bsm[(h0 + 3) * 1060 + snn * 33 + mm] = v4.w;
            }
        }
        __syncthreads();  // bsm ready

        bf16x8 kf[2][2], vf[4];
#pragma unroll
        for (int ct = 0; ct < 2; ++ct)
#pragma unroll
            for (int kc = 0; kc < 2; ++kc)
                kf[ct][kc] = *reinterpret_cast<const bf16x8*>(
                    kw + (bh * 1024 + m0 + ct * 16 + l16) * 64 + kc * 32 + g * 8);
#pragma unroll
        for (int oc = 0; oc < 4; ++oc)
            vf[oc] = *reinterpret_cast<const bf16x8*>(
                vtw + (bh * 64 + oc * 16 + l16) * 1024 + m0 + g * 8);

        f32x4 s[2][2] = {};
#pragma unroll
        for (int rt = 0; rt < 2; ++rt)
#pragma unroll
            for (int ct = 0; ct < 2; ++ct) {
                s[rt][ct] = MFMA16(qf[rt][0], kf[ct][0], s[rt][ct]);
                s[rt][ct] = MFMA16(qf[rt][1], kf[ct][1], s[rt][ct]);
            }

        // bias add + online softmax (row n = rt*16 + 4g + reg, shared by 16 lanes)
#pragma unroll
        for (int rt = 0; rt < 2; ++rt) {
#pragma unroll
            for (int reg = 0; reg < 4; ++reg) {
                const int nrow = rt * 16 + 4 * g + reg;
                float s0 = s[rt][0][reg] + bsm[w * 1060 + nrow * 33 + l16];
                float s1 = s[rt][1][reg] + bsm[w * 1060 + nrow * 33 + 16 + l16];
                float t = fmaxf(s0, s1);
                t = fmaxf(t, __shfl_xor(t, 1));
                t = fmaxf(t, __shfl_xor(t, 2));
                t = fmaxf(t, __shfl_xor(t, 4));
                t = fmaxf(t, __shfl_xor(t, 8));
                float mold = mrun[rt][reg];
                float mnew = fmaxf(mold, t);
                float alpha = __expf(mold - mnew);
                float p0 = __expf(s0 - mnew);
                float p1 = __expf(s1 - mnew);
                float rs = p0 + p1;
                rs += __shfl_xor(rs, 1);
                rs += __shfl_xor(rs, 2);
                rs += __shfl_xor(rs, 4);
                rs += __shfl_xor(rs, 8);
                lrun[rt][reg] = lrun[rt][reg] * alpha + rs;
                mrun[rt][reg] = mnew;
#pragma unroll
                for (int oc = 0; oc < 4; ++oc) o[rt][oc][reg] *= alpha;
                psm[w][nrow][l16]      = (__bf16)p0;
                psm[w][nrow][16 + l16] = (__bf16)p1;
            }
        }
        __syncthreads();  // psm visible (conservative; per-wave region)

        bf16x8 pf[2];
#pragma unroll
        for (int rt = 0; rt < 2; ++rt)
            pf[rt] = *reinterpret_cast<const bf16x8*>(&psm[w][rt * 16 + l16][g * 8]);
#pragma unroll
        for (int rt = 0; rt < 2; ++rt)
#pragma unroll
            for (int oc = 0; oc < 4; ++oc)
                o[rt][oc] = MFMA16(pf[rt], vf[oc], o[rt][oc]);
    }

    // normalize + store  [b][n][h*64+dh] bf16
#pragma unroll
    for (int rt = 0; rt < 2; ++rt)
#pragma unroll
        for (int oc = 0; oc < 4; ++oc)
#pragma unroll
            for (int reg = 0; reg < 4; ++reg) {
                int n  = n0 + rt * 16 + 4 * g + reg;
                int dh = oc * 16 + l16;
                float val = o[rt][oc][reg] / lrun[rt][reg];
                ow[((size_t)b * 1024 + n) * 512 + w * 64 + dh] = (__bf16)val;
            }
}

// ---------------------------------------------------------------------------
// Kernel 4: output projection.  out = O @ Wm^T + bm  (O bf16, out f32)
// ---------------------------------------------------------------------------
__global__ __launch_bounds__(256) void gemm_out(
    const __bf16* __restrict__ a, const float* __restrict__ Wm,
    const float* __restrict__ bm, float* __restrict__ out)
{
    __shared__ __bf16 As[64][40];
    __shared__ __bf16 Bs[64][40];
    const int tid  = threadIdx.x;
    const int lane = tid & 63;
    const int wid  = tid >> 6;
    const int g    = lane >> 4, l16 = lane & 15;
    const int wr   = wid >> 1,  wc  = wid & 1;
    const int r0   = blockIdx.x * 64;
    const int c0   = blockIdx.y * 64;

    const int sra = tid >> 2, sca = tid & 3;  // A: 64 rows x 4 chunks of 8 bf16
    const int srb = tid >> 3, scb = tid & 7;  // B: 32 rows x 8 float4, 2 passes

    f32x4 acc[2][2] = {};
    for (int k0 = 0; k0 < 512; k0 += 32) {
        __syncthreads();
        {
            bf16x8 av = *reinterpret_cast<const bf16x8*>(a + (size_t)(r0 + sra) * 512 + k0 + sca * 8);
            *reinterpret_cast<bf16x8*>(&As[sra][sca * 8]) = av;
#pragma unroll
            for (int j = 0; j < 2; ++j) {
                int r = srb + 32 * j;
                float4 bv = *reinterpret_cast<const float4*>(Wm + (size_t)(c0 + r) * 512 + k0 + scb * 4);
                bf16x4 bp = { (__bf16)bv.x, (__bf16)bv.y, (__bf16)bv.z, (__bf16)bv.w };
                *reinterpret_cast<bf16x4*>(&Bs[r][scb * 4]) = bp;
            }
        }
        __syncthreads();
        bf16x8 af[2], bfr[2];
#pragma unroll
        for (int rt = 0; rt < 2; ++rt)
            af[rt] = *reinterpret_cast<const bf16x8*>(&As[wr * 32 + rt * 16 + l16][g * 8]);
#pragma unroll
        for (int ct = 0; ct < 2; ++ct)
            bfr[ct] = *reinterpret_cast<const bf16x8*>(&Bs[wc * 32 + ct * 16 + l16][g * 8]);
#pragma unroll
        for (int rt = 0; rt < 2; ++rt)
#pragma unroll
            for (int ct = 0; ct < 2; ++ct)
                acc[rt][ct] = MFMA16(af[rt], bfr[ct], acc[rt][ct]);
    }

#pragma unroll
    for (int rt = 0; rt < 2; ++rt)
#pragma unroll
        for (int ct = 0; ct < 2; ++ct)
#pragma unroll
            for (int reg = 0; reg < 4; ++reg) {
                int r = r0 + wr * 32 + rt * 16 + 4 * g + reg;
                int c = c0 + wc * 32 + ct * 16 + l16;
                out[(size_t)r * 512 + c] = acc[rt][ct][reg] + bm[c];
            }
}

// ---------------------------------------------------------------------------
extern "C" void kernel_launch(void* const* d_in, const int* in_sizes, int n_in,
                              void* d_out, int out_size, void* d_ws, size_t ws_size,
                              hipStream_t stream)
{
    const float* x    = (const float*)d_in[0];
    const float* bias = (const float*)d_in[1];
    const float* Wq   = (const float*)d_in[2];
    const float* Wk   = (const float*)d_in[3];
    const float* Wv   = (const float*)d_in[4];
    const float* Wm   = (const float*)d_in[5];
    const float* bm   = (const float*)d_in[6];
    float* out = (float*)d_out;

    const size_t SEG = (size_t)8 * 8 * 1024 * 64;  // 4M bf16 elems per tensor
    __bf16* qw  = (__bf16*)d_ws;
    __bf16* kw  = qw + SEG;
    __bf16* vw  = kw + SEG;
    __bf16* vtw = vw + SEG;
    __bf16* ow  = vw;  // alias: v is dead after transpose

    gemm_qkv  <<<dim3(128, 24), 256, 0, stream>>>(x, Wq, Wk, Wv, qw, kw, vw);
    transpose_v<<<dim3(16, 64), 256, 0, stream>>>(vw, vtw);
    attn_kernel<<<dim3(32, 8), 512, 0, stream>>>(qw, kw, vtw, bias, ow);
    gemm_out  <<<dim3(128, 8), 256, 0, stream>>>(ow, Wm, bm, out);
}